// Round 3
// baseline (330.144 us; speedup 1.0000x reference)
//
#include <hip/hip_runtime.h>
#include <hip/hip_bf16.h>
#include <hip/hip_fp16.h>
#include <math.h>

#define N_NODES 50000
#define N_EDGES 800000
#define HID 64
#define NBK 196          // buckets of 256 nodes
#define EPB 1024         // edges per hist/scatter block
#define SB  ((N_EDGES + EPB - 1) / EPB)   // 782
#define FLAT (NBK * SB)  // 153272 flattened (bucket-major) histogram entries
#define SCAN_B ((FLAT + 255) / 256)  // 599

#define QKVS0_BLKS 3125

// fused prep grid partition
#define LN0_BLKS   6250
#define HIST_BLKS  SB
#define WP0_BLKS   32    // 16*1*512 / 256
#define WP12_BLKS  64    // 16*2*512 / 256
#define PREP_BLKS  (LN0_BLKS + HIST_BLKS + WP0_BLKS + 2 * WP12_BLKS)

typedef __attribute__((ext_vector_type(8))) short short8;
typedef __attribute__((ext_vector_type(4))) float float4v;
typedef __attribute__((ext_vector_type(2))) float float2v;

__device__ __forceinline__ unsigned short f32_to_bf16_rne(float f) {
    unsigned int u = __float_as_uint(f);
    unsigned int r = u + 0x7fffu + ((u >> 16) & 1u);
    return (unsigned short)(r >> 16);
}

// fp8 e4m3fn (OCP on gfx950) helpers: HW cvt instructions.
__device__ __forceinline__ unsigned int f32_to_fp8_byte(float f) {
    return (unsigned int)__builtin_amdgcn_cvt_pk_fp8_f32(f, f, 0, false) & 0xffu;
}
template <bool HI>
__device__ __forceinline__ float2v fp8x2_to_f32(unsigned int w) {
    return __builtin_amdgcn_cvt_pk_f32_fp8((int)w, HI);
}
__device__ __forceinline__ float2 h2_to_f32(unsigned int w) {
    __half2 h = *reinterpret_cast<__half2*>(&w);
    return __half22float2(h);
}

// ---------------------------------------------------------------------------
// Device helpers for the fused prep kernel.
__device__ __forceinline__ void ln0_body(int b, int t,
        const float* __restrict__ x, const float* __restrict__ g,
        const float* __restrict__ bb, float* __restrict__ h0) {
    int lane = t & 63;
    int n = b * 8 + (t >> 6) * 2 + (lane >> 5);
    int c = lane & 31;
    float v = x[n * 32 + c];
    float s = v;
    #pragma unroll
    for (int off = 1; off < 32; off <<= 1) s += __shfl_xor(s, off);
    float mu = s * (1.0f / 32.0f);
    float d = v - mu;
    float vs = d * d;
    #pragma unroll
    for (int off = 1; off < 32; off <<= 1) vs += __shfl_xor(vs, off);
    float var = vs * (1.0f / 32.0f);
    h0[n * 32 + c] = d * rsqrtf(var + 1e-5f) * g[c] + bb[c];
}

__device__ __forceinline__ void wprep_body(int idx, int KS,
        const float* __restrict__ Wq, const float* __restrict__ Wk,
        const float* __restrict__ Wv, const float* __restrict__ Ws,
        unsigned short* __restrict__ Wp) {
    int j = idx & 7;
    int lane = (idx >> 3) & 63;
    int ts = idx >> 9;            // tile*KS + s
    int s = ts % KS;
    int tile = ts / KS;
    int which = tile >> 2;
    int slice = tile & 3;
    int k = s * 32 + ((lane >> 4) * 8) + j;
    int col = slice * 16 + (lane & 15);
    const float* W = (which == 0) ? Wq : (which == 1) ? Wk : (which == 2) ? Wv : Ws;
    Wp[idx] = f32_to_bf16_rne(W[k * 64 + col]);
}

// ---------------------------------------------------------------------------
// Fused prep: ln0 + per-block bucket histogram + 3x weight pack.
__global__ __launch_bounds__(256) void prep_kernel(
        const float* __restrict__ x, const float* __restrict__ ln0g,
        const float* __restrict__ ln0b, float* __restrict__ h0,
        const int* __restrict__ dst, int* __restrict__ ghist,
        const float* __restrict__ Wq0, const float* __restrict__ Wk0,
        const float* __restrict__ Wv0, const float* __restrict__ Ws0,
        unsigned short* __restrict__ Wp0,
        const float* __restrict__ Wq1, const float* __restrict__ Wk1,
        const float* __restrict__ Wv1, const float* __restrict__ Ws1,
        unsigned short* __restrict__ Wp1,
        const float* __restrict__ Wq2, const float* __restrict__ Wk2,
        const float* __restrict__ Wv2, const float* __restrict__ Ws2,
        unsigned short* __restrict__ Wp2) {
    __shared__ int hist[NBK];
    int b = blockIdx.x;
    int t = threadIdx.x;
    if (b < LN0_BLKS) {
        ln0_body(b, t, x, ln0g, ln0b, h0);
    } else if (b < LN0_BLKS + HIST_BLKS) {
        int i = b - LN0_BLKS;
        for (int k = t; k < NBK; k += 256) hist[k] = 0;
        __syncthreads();
        int e0 = i * EPB;
        #pragma unroll
        for (int r = 0; r < EPB / 256; r++) {
            int e = e0 + r * 256 + t;
            if (e < N_EDGES) atomicAdd(&hist[dst[e] >> 8], 1);
        }
        __syncthreads();
        for (int k = t; k < NBK; k += 256) ghist[k * SB + i] = hist[k];
    } else if (b < LN0_BLKS + HIST_BLKS + WP0_BLKS) {
        int idx = (b - LN0_BLKS - HIST_BLKS) * 256 + t;
        wprep_body(idx, 1, Wq0, Wk0, Wv0, Ws0, Wp0);
    } else if (b < LN0_BLKS + HIST_BLKS + WP0_BLKS + WP12_BLKS) {
        int idx = (b - LN0_BLKS - HIST_BLKS - WP0_BLKS) * 256 + t;
        wprep_body(idx, 2, Wq1, Wk1, Wv1, Ws1, Wp1);
    } else {
        int idx = (b - LN0_BLKS - HIST_BLKS - WP0_BLKS - WP12_BLKS) * 256 + t;
        wprep_body(idx, 2, Wq2, Wk2, Wv2, Ws2, Wp2);
    }
}

// ---------------------------------------------------------------------------
// CSR build scans (deterministic, no global atomics).
__global__ void scan1_kernel(const int* __restrict__ ghist, int* __restrict__ csum) {
    int f = blockIdx.x * 256 + threadIdx.x;
    int v = (f < FLAT) ? ghist[f] : 0;
    #pragma unroll
    for (int off = 1; off < 64; off <<= 1) v += __shfl_xor(v, off);
    __shared__ int ws[4];
    if ((threadIdx.x & 63) == 0) ws[threadIdx.x >> 6] = v;
    __syncthreads();
    if (threadIdx.x == 0) csum[blockIdx.x] = ws[0] + ws[1] + ws[2] + ws[3];
}

__global__ void scan2_kernel(const int* __restrict__ csum, int* __restrict__ coff,
                             int* __restrict__ bbase, int* __restrict__ row_ptr) {
    int lane = threadIdx.x;
    int carry = 0;
    for (int base = 0; base < SCAN_B; base += 64) {
        int i = base + lane;
        int v = (i < SCAN_B) ? csum[i] : 0;
        int incl = v;
        #pragma unroll
        for (int off = 1; off < 64; off <<= 1) {
            int tt = __shfl_up(incl, off);
            if (lane >= off) incl += tt;
        }
        if (i < SCAN_B) coff[i] = carry + incl - v;
        carry += __shfl(incl, 63);
    }
    if (lane == 0) { bbase[NBK] = N_EDGES; row_ptr[N_NODES] = N_EDGES; }
}

__global__ void scan3_kernel(const int* __restrict__ ghist, const int* __restrict__ coff,
                             int* __restrict__ goff, int* __restrict__ bbase) {
    int f = blockIdx.x * 256 + threadIdx.x;
    int lane = threadIdx.x & 63;
    int w = threadIdx.x >> 6;
    int v = (f < FLAT) ? ghist[f] : 0;
    int incl = v;
    #pragma unroll
    for (int off = 1; off < 64; off <<= 1) {
        int tt = __shfl_up(incl, off);
        if (lane >= off) incl += tt;
    }
    __shared__ int ws[4];
    if (lane == 63) ws[w] = incl;
    __syncthreads();
    int woff = 0;
    #pragma unroll
    for (int k = 0; k < 4; k++) if (k < w) woff += ws[k];
    int excl = coff[blockIdx.x] + woff + incl - v;
    if (f < FLAT) {
        goff[f] = excl;
        if (f % SB == 0) bbase[f / SB] = excl;
    }
}

// ---------------------------------------------------------------------------
// Q/K/V/Skip projection body via MFMA. Block = 16 nodes; wave w owns the
// 16-col slice w of each of Q,K,V,S. fp32 accum; biases in fp32.
// Outputs (precision re-budget: streams are free [R1], gathers are the wall):
//   Qf, Sf : f32 streams (Q pre-scaled by 1/sqrt(C))
//   K8     : fp8 e4m3 row of 64B  = 1 cache line/edge; 3.2MB table ~ L2-fits
//   Vh     : fp16 row of 128B     = 2 cache lines/edge
template <int D>
__device__ __forceinline__ void qkvs_body(int bid, int t,
        const float* __restrict__ h,
        const unsigned short* __restrict__ Wp,
        const float* __restrict__ bq, const float* __restrict__ bk,
        const float* __restrict__ bv, float scale,
        float* __restrict__ Qf, float* __restrict__ Sf,
        unsigned int* __restrict__ K8, uint2* __restrict__ Vh) {
    constexpr int KS = D / 32;
    int lane = t & 63;
    int w = t >> 6;
    int n0 = bid * 16;
    int n16 = lane & 15;
    int quad = lane >> 4;
    int col = w * 16 + n16;

    short8 afrag[KS];
    #pragma unroll
    for (int s = 0; s < KS; s++) {
        const float* hp = &h[(n0 + n16) * D + s * 32 + quad * 8];
        float4 a0 = *(const float4*)hp;
        float4 a1 = *(const float4*)(hp + 4);
        short8 af;
        af[0] = (short)f32_to_bf16_rne(a0.x);
        af[1] = (short)f32_to_bf16_rne(a0.y);
        af[2] = (short)f32_to_bf16_rne(a0.z);
        af[3] = (short)f32_to_bf16_rne(a0.w);
        af[4] = (short)f32_to_bf16_rne(a1.x);
        af[5] = (short)f32_to_bf16_rne(a1.y);
        af[6] = (short)f32_to_bf16_rne(a1.z);
        af[7] = (short)f32_to_bf16_rne(a1.w);
        afrag[s] = af;
    }

    float4v accs[4];
    #pragma unroll
    for (int which = 0; which < 4; which++) {
        float4v acc = {0.0f, 0.0f, 0.0f, 0.0f};
        int tile = which * 4 + w;
        #pragma unroll
        for (int s = 0; s < KS; s++) {
            short8 bfrag = *(const short8*)&Wp[((tile * KS + s) * 64 + lane) * 8];
            acc = __builtin_amdgcn_mfma_f32_16x16x32_bf16(afrag[s], bfrag, acc, 0, 0, 0);
        }
        accs[which] = acc;
    }

    float bqc = bq[col], bkc = bk[col], bvc = bv[col];
    int j = n16 & 3;                    // byte/half position within 4-channel word
    int mword = (col >> 2);             // 4-channel word index 0..15

    #pragma unroll
    for (int r = 0; r < 4; r++) {
        int node = n0 + quad * 4 + r;
        Qf[node * 64 + col] = (accs[0][r] + bqc) * scale;
        Sf[node * 64 + col] = accs[3][r];
        // fp8-pack K: 4 consecutive channels -> one dword, via shfl-OR
        unsigned int ku = f32_to_fp8_byte(accs[1][r] + bkc) << (8 * j);
        ku |= __shfl_xor(ku, 1); ku |= __shfl_xor(ku, 2);
        // fp16-pack V: 4 consecutive channels -> uint2 {c0|c1<<16, c2|c3<<16}
        unsigned int hb = (unsigned int)__half_as_ushort(__float2half_rn(accs[2][r] + bvc));
        unsigned int vx = (j < 2) ? (hb << (16 * j)) : 0u;
        unsigned int vy = (j >= 2) ? (hb << (16 * (j - 2))) : 0u;
        vx |= __shfl_xor(vx, 1); vx |= __shfl_xor(vx, 2);
        vy |= __shfl_xor(vy, 1); vy |= __shfl_xor(vy, 2);
        if (j == 0) {
            K8[node * 16 + mword] = ku;
            Vh[node * 16 + mword] = make_uint2(vx, vy);
        }
    }
}

template <int D>
__global__ __launch_bounds__(256) void qkvs_mfma_kernel(
        const float* __restrict__ h,
        const unsigned short* __restrict__ Wp,
        const float* __restrict__ bq, const float* __restrict__ bk,
        const float* __restrict__ bv, float scale,
        float* __restrict__ Qf, float* __restrict__ Sf,
        unsigned int* __restrict__ K8, uint2* __restrict__ Vh) {
    qkvs_body<D>(blockIdx.x, threadIdx.x, h, Wp, bq, bk, bv, scale, Qf, Sf, K8, Vh);
}

// ---------------------------------------------------------------------------
// Fused scatter + layer-0 QKVS (independent work; fills the CUs).
__global__ __launch_bounds__(256) void scatter_qkvs0_kernel(
        const int* __restrict__ src, const int* __restrict__ dst,
        const int* __restrict__ goff, int2* __restrict__ ebkt,
        const float* __restrict__ h, const unsigned short* __restrict__ Wp,
        const float* __restrict__ bq, const float* __restrict__ bk,
        const float* __restrict__ bv, float scale,
        float* __restrict__ Qf, float* __restrict__ Sf,
        unsigned int* __restrict__ K8, uint2* __restrict__ Vh) {
    __shared__ int hist[NBK];
    int t = threadIdx.x;
    if (blockIdx.x < SB) {
        int i = blockIdx.x;
        for (int k = t; k < NBK; k += 256) hist[k] = 0;
        __syncthreads();
        int e0 = i * EPB;
        #pragma unroll
        for (int r = 0; r < EPB / 256; r++) {
            int e = e0 + r * 256 + t;
            if (e < N_EDGES) {
                int s = src[e], d = dst[e];
                int k = d >> 8;
                int rank = atomicAdd(&hist[k], 1);
                ebkt[goff[k * SB + i] + rank] = make_int2(s, d);
            }
        }
    } else {
        qkvs_body<32>(blockIdx.x - SB, t, h, Wp, bq, bk, bv, scale, Qf, Sf, K8, Vh);
    }
}

__global__ __launch_bounds__(256) void bucket_build_kernel(
        const int2* __restrict__ ebkt, const int* __restrict__ bbase,
        int* __restrict__ row_ptr, int* __restrict__ colb) {
    __shared__ int ldeg[256];
    __shared__ int lcur[256];
    __shared__ int wsum[4];
    int b = blockIdx.x;
    int t = threadIdx.x;
    int cbase = bbase[b];
    int cnt = bbase[b + 1] - cbase;

    ldeg[t] = 0;
    __syncthreads();
    for (int i = t; i < cnt; i += 256) {
        int2 e = ebkt[cbase + i];
        atomicAdd(&ldeg[e.y & 255], 1);
    }
    __syncthreads();

    int lane = t & 63;
    int w = t >> 6;
    int v = ldeg[t];
    int incl = v;
    #pragma unroll
    for (int off = 1; off < 64; off <<= 1) {
        int tt = __shfl_up(incl, off);
        if (lane >= off) incl += tt;
    }
    if (lane == 63) wsum[w] = incl;
    __syncthreads();
    int woff = 0;
    #pragma unroll
    for (int k = 0; k < 4; k++) if (k < w) woff += wsum[k];
    int excl = woff + incl - v;

    int node = b * 256 + t;
    if (node < N_NODES) row_ptr[node] = cbase + excl;
    lcur[t] = excl;
    __syncthreads();

    for (int i = t; i < cnt; i += 256) {
        int2 e = ebkt[cbase + i];
        int r = atomicAdd(&lcur[e.y & 255], 1);
        colb[cbase + r] = e.x;
    }
}

// ---------------------------------------------------------------------------
// Kernel: per-node attention aggregation + skip + LayerNorm (+res/relu).
// One wave per node, 4 groups of 16 lanes; 16-edge batched gathers.
// K gather = 1 line/edge (fp8, 64B row, table ~L2-resident);
// V gather = 2 lines/edge (fp16, 128B row). 3 lines/edge vs 4 in R1.
template <int HEADS, bool RES, bool RELU, bool HEAD>
__global__ __launch_bounds__(256) void agg_kernel(
                           const float* __restrict__ Qf,
                           const float* __restrict__ Sf,
                           const unsigned int* __restrict__ K8,
                           const uint2* __restrict__ Vh,
                           const int* __restrict__ row_ptr, const int* __restrict__ colb,
                           const float* __restrict__ g, const float* __restrict__ b,
                           const float* __restrict__ h_in, float* __restrict__ h_out,
                           const float* __restrict__ Wr1, const float* __restrict__ br1,
                           const float* __restrict__ Wr2, const float* __restrict__ br2,
                           const float* __restrict__ Wt1, const float* __restrict__ bt1,
                           const float* __restrict__ Wt2, const float* __restrict__ bt2,
                           float* __restrict__ out) {
    constexpr int C = HID / HEADS;
    int lane = threadIdx.x & 63;
    int m = lane & 15;
    int grp = lane >> 4;
    int n = blockIdx.x * 4 + (threadIdx.x >> 6);

    float4 q4 = *(const float4*)&Qf[n * 64 + 4 * m];

    int beg = row_ptr[n], end = row_ptr[n + 1];

    float ssum = 0.0f;
    float acc0 = 0.0f, acc1 = 0.0f, acc2 = 0.0f, acc3 = 0.0f;

    for (int base = beg; base < end; base += 64) {
        int limit = min(end - base, 64);
        int src_l = (base + lane < end) ? colb[base + lane] : 0;
        for (int sub = 0; sub < limit; sub += 16) {
            int e0 = sub + grp, e1 = sub + 4 + grp, e2 = sub + 8 + grp, e3 = sub + 12 + grp;
            int s0 = __shfl(src_l, e0);
            int s1 = __shfl(src_l, e1);
            int s2 = __shfl(src_l, e2);
            int s3 = __shfl(src_l, e3);
            bool v0ok = e0 < limit, v1ok = e1 < limit, v2ok = e2 < limit, v3ok = e3 < limit;
            unsigned int ka0 = 0, ka1 = 0, ka2 = 0, ka3 = 0;
            uint2 va0 = make_uint2(0, 0), va1 = va0, va2 = va0, va3 = va0;
            if (v0ok) { ka0 = K8[(size_t)s0 * 16 + m]; va0 = Vh[(size_t)s0 * 16 + m]; }
            if (v1ok) { ka1 = K8[(size_t)s1 * 16 + m]; va1 = Vh[(size_t)s1 * 16 + m]; }
            if (v2ok) { ka2 = K8[(size_t)s2 * 16 + m]; va2 = Vh[(size_t)s2 * 16 + m]; }
            if (v3ok) { ka3 = K8[(size_t)s3 * 16 + m]; va3 = Vh[(size_t)s3 * 16 + m]; }

            float2v k0a = fp8x2_to_f32<false>(ka0), k0b = fp8x2_to_f32<true>(ka0);
            float2v k1a = fp8x2_to_f32<false>(ka1), k1b = fp8x2_to_f32<true>(ka1);
            float2v k2a = fp8x2_to_f32<false>(ka2), k2b = fp8x2_to_f32<true>(ka2);
            float2v k3a = fp8x2_to_f32<false>(ka3), k3b = fp8x2_to_f32<true>(ka3);

            float t0 = fmaf(q4.x, k0a.x, fmaf(q4.y, k0a.y,
                       fmaf(q4.z, k0b.x, q4.w * k0b.y)));
            float t1 = fmaf(q4.x, k1a.x, fmaf(q4.y, k1a.y,
                       fmaf(q4.z, k1b.x, q4.w * k1b.y)));
            float t2 = fmaf(q4.x, k2a.x, fmaf(q4.y, k2a.y,
                       fmaf(q4.z, k2b.x, q4.w * k2b.y)));
            float t3 = fmaf(q4.x, k3a.x, fmaf(q4.y, k3a.y,
                       fmaf(q4.z, k3b.x, q4.w * k3b.y)));
            #pragma unroll
            for (int off = 1; off < C / 4; off <<= 1) {
                t0 += __shfl_xor(t0, off);
                t1 += __shfl_xor(t1, off);
                t2 += __shfl_xor(t2, off);
                t3 += __shfl_xor(t3, off);
            }
            float p0 = v0ok ? __expf(t0) : 0.0f;
            float p1 = v1ok ? __expf(t1) : 0.0f;
            float p2 = v2ok ? __expf(t2) : 0.0f;
            float p3 = v3ok ? __expf(t3) : 0.0f;
            ssum += (p0 + p1) + (p2 + p3);

            float2 v0a = h2_to_f32(va0.x), v0b = h2_to_f32(va0.y);
            float2 v1a = h2_to_f32(va1.x), v1b = h2_to_f32(va1.y);
            float2 v2a = h2_to_f32(va2.x), v2b = h2_to_f32(va2.y);
            float2 v3a = h2_to_f32(va3.x), v3b = h2_to_f32(va3.y);

            acc0 = fmaf(p0, v0a.x, fmaf(p1, v1a.x,
                   fmaf(p2, v2a.x, fmaf(p3, v3a.x, acc0))));
            acc1 = fmaf(p0, v0a.y, fmaf(p1, v1a.y,
                   fmaf(p2, v2a.y, fmaf(p3, v3a.y, acc1))));
            acc2 = fmaf(p0, v0b.x, fmaf(p1, v1b.x,
                   fmaf(p2, v2b.x, fmaf(p3, v3b.x, acc2))));
            acc3 = fmaf(p0, v0b.y, fmaf(p1, v1b.y,
                   fmaf(p2, v2b.y, fmaf(p3, v3b.y, acc3))));
        }
    }

    #pragma unroll
    for (int off = 16; off < 64; off <<= 1) {
        ssum += __shfl_xor(ssum, off);
        acc0 += __shfl_xor(acc0, off);
        acc1 += __shfl_xor(acc1, off);
        acc2 += __shfl_xor(acc2, off);
        acc3 += __shfl_xor(acc3, off);
    }

    float inv = 1.0f / (ssum + 1e-16f);
    float4 sv = *(const float4*)&Sf[n * 64 + 4 * m];
    float o0 = fmaf(acc0, inv, sv.x);
    float o1 = fmaf(acc1, inv, sv.y);
    float o2 = fmaf(acc2, inv, sv.z);
    float o3 = fmaf(acc3, inv, sv.w);

    float s = (o0 + o1) + (o2 + o3);
    #pragma unroll
    for (int off = 1; off < 16; off <<= 1) s += __shfl_xor(s, off);
    float mu = s * (1.0f / 64.0f);
    float d0 = o0 - mu, d1 = o1 - mu, d2 = o2 - mu, d3 = o3 - mu;
    float vs = (d0 * d0 + d1 * d1) + (d2 * d2 + d3 * d3);
    #pragma unroll
    for (int off = 1; off < 16; off <<= 1) vs += __shfl_xor(vs, off);
    float rstd = rsqrtf(vs * (1.0f / 64.0f) + 1e-5f);

    float4 gv = *(const float4*)&g[4 * m];
    float4 bv = *(const float4*)&b[4 * m];
    float y0 = d0 * rstd * gv.x + bv.x;
    float y1 = d1 * rstd * gv.y + bv.y;
    float y2 = d2 * rstd * gv.z + bv.z;
    float y3 = d3 * rstd * gv.w + bv.w;
    if (RES) {
        float4 rv = *(const float4*)&h_in[n * 64 + 4 * m];
        y0 = fmaf(0.1f, rv.x, y0);
        y1 = fmaf(0.1f, rv.y, y1);
        y2 = fmaf(0.1f, rv.z, y2);
        y3 = fmaf(0.1f, rv.w, y3);
    }
    if (RELU) {
        y0 = fmaxf(y0, 0.0f); y1 = fmaxf(y1, 0.0f);
        y2 = fmaxf(y2, 0.0f); y3 = fmaxf(y3, 0.0f);
    }

    if (!HEAD) {
        if (grp == 0) {
            float4 yv = make_float4(y0, y1, y2, y3);
            *(float4*)&h_out[n * 64 + 4 * m] = yv;
        }
    } else {
        __shared__ float sh[4][HID];
        int wave = threadIdx.x >> 6;
        if (grp == 0) {
            float4 yv = make_float4(y0, y1, y2, y3);
            *(float4*)&sh[wave][4 * m] = yv;
        }
        __syncthreads();
        int half = lane >> 5;
        int j = lane & 31;
        const float* W1 = half ? Wt1 : Wr1;
        const float* b1 = half ? bt1 : br1;
        const float* W2 = half ? Wt2 : Wr2;
        const float* b2v = half ? bt2 : br2;
        float a = b1[j];
        #pragma unroll 8
        for (int i = 0; i < 64; i++) a = fmaf(sh[wave][i], W1[i * 32 + j], a);
        a = fmaxf(a, 0.0f);
        float r = a * W2[j];
        #pragma unroll
        for (int off = 1; off < 32; off <<= 1) r += __shfl_xor(r, off);
        if (j == 0) out[n * 2 + half] = r + b2v[0];
    }
}

// ---------------------------------------------------------------------------
extern "C" void kernel_launch(void* const* d_in, const int* in_sizes, int n_in,
                              void* d_out, int out_size, void* d_ws, size_t ws_size,
                              hipStream_t stream) {
    const float* x    = (const float*)d_in[0];
    const int*   ei   = (const int*)d_in[1];
    const int*   src  = ei;
    const int*   dst  = ei + N_EDGES;
    const float* ln0g = (const float*)d_in[2];
    const float* ln0b = (const float*)d_in[3];

    const float* P[27];
    for (int i = 0; i < 27; i++) P[i] = (const float*)d_in[4 + i];
    const float* Wr1 = (const float*)d_in[31];
    const float* br1 = (const float*)d_in[32];
    const float* Wr2 = (const float*)d_in[33];
    const float* br2 = (const float*)d_in[34];
    const float* Wt1 = (const float*)d_in[35];
    const float* bt1 = (const float*)d_in[36];
    const float* Wt2 = (const float*)d_in[37];
    const float* bt2 = (const float*)d_in[38];

    float* out = (float*)d_out;

    // workspace layout
    float* hbuf0 = (float*)d_ws;                 // N*64
    float* hbuf1 = hbuf0 + N_NODES * 64;         // N*64
    float* Qf    = hbuf1 + N_NODES * 64;         // N*64 f32
    float* Sf    = Qf + N_NODES * 64;            // N*64 f32
    unsigned int* K8 = (unsigned int*)(Sf + N_NODES * 64);  // N*16 uint (64B fp8 rows)
    uint2* Vh    = (uint2*)(K8 + N_NODES * 16);  // N*16 uint2 (128B fp16 rows)
    int* row_ptr = (int*)(Vh + N_NODES * 16);    // N+1
    int* colb    = row_ptr + (N_NODES + 1);      // E
    int* ghist   = colb + N_EDGES;               // FLAT
    int* goff    = ghist + FLAT;                 // FLAT
    int* csum    = goff + FLAT;                  // SCAN_B
    int* coff    = csum + SCAN_B;                // SCAN_B
    int* bbase   = coff + SCAN_B;                // NBK+1
    unsigned short* Wp0 = (unsigned short*)(bbase + NBK + 1); // 16*1*512
    unsigned short* Wp1 = Wp0 + 16 * 1 * 512;                 // 16*2*512
    unsigned short* Wp2 = Wp1 + 16 * 2 * 512;                 // 16*2*512
    // ebkt aliases hbuf1 (dead until agg0 writes it): E int2 = 6.4 MB < 12.8 MB
    int2* ebkt = (int2*)hbuf1;

    // ---- fused prep (ln0 + bucket hist + weight packs) ----
    prep_kernel<<<PREP_BLKS, 256, 0, stream>>>(x, ln0g, ln0b, hbuf0,
        dst, ghist,
        P[0],  P[2],  P[4],  P[6],  Wp0,
        P[9],  P[11], P[13], P[15], Wp1,
        P[18], P[20], P[22], P[24], Wp2);
    // ---- CSR build (deterministic counting sort, separate kernels) ----
    scan1_kernel<<<SCAN_B, 256, 0, stream>>>(ghist, csum);
    scan2_kernel<<<1, 64, 0, stream>>>(csum, coff, bbase, row_ptr);
    scan3_kernel<<<SCAN_B, 256, 0, stream>>>(ghist, coff, goff, bbase);
    // ---- scatter + layer-0 QKVS fused (independent work, fills the CUs) ----
    scatter_qkvs0_kernel<<<SB + QKVS0_BLKS, 256, 0, stream>>>(src, dst, goff, ebkt,
        hbuf0, Wp0, P[1], P[3], P[5], 0.25f, Qf, Sf, K8, Vh);
    bucket_build_kernel<<<NBK, 256, 0, stream>>>(ebkt, bbase, row_ptr, colb);

    // ---- layer 0: 32 -> 64, heads=4, no residual, relu ----
    agg_kernel<4, false, true, false><<<12500, 256, 0, stream>>>(Qf, Sf, K8, Vh,
        row_ptr, colb, P[7], P[8], nullptr, hbuf1,
        Wr1, br1, Wr2, br2, Wt1, bt1, Wt2, bt2, out);

    // ---- layer 1: 64 -> 64, heads=4, residual, relu ----
    qkvs_mfma_kernel<64><<<3125, 256, 0, stream>>>(hbuf1, Wp1,
        P[10], P[12], P[14], 0.25f, Qf, Sf, K8, Vh);
    agg_kernel<4, true, true, false><<<12500, 256, 0, stream>>>(Qf, Sf, K8, Vh,
        row_ptr, colb, P[16], P[17], hbuf1, hbuf0,
        Wr1, br1, Wr2, br2, Wt1, bt1, Wt2, bt2, out);

    // ---- layer 2: 64 -> 64, heads=1, residual, no relu + fused MLP heads ----
    qkvs_mfma_kernel<64><<<3125, 256, 0, stream>>>(hbuf0, Wp2,
        P[19], P[21], P[23], 0.125f, Qf, Sf, K8, Vh);
    agg_kernel<1, true, false, true><<<12500, 256, 0, stream>>>(Qf, Sf, K8, Vh,
        row_ptr, colb, P[25], P[26], hbuf0, hbuf1,
        Wr1, br1, Wr2, br2, Wt1, bt1, Wt2, bt2, out);
}